// Round 4
// baseline (1090.136 us; speedup 1.0000x reference)
//
#include <hip/hip_runtime.h>
#include <math.h>

// CSCR fused persistent kernel. B=32, C=256, H=W=56 (HW=3136).
// Output = concat(rgb_out, ir_out). Dual-dtype (bf16/fp32) runtime-detected.
// ONE kernel, 1024 blocks x 256 thr (4/CU guaranteed: VGPR<=128 via
// launch_bounds, LDS 14.6KB), manual grid barrier in workspace (sense-
// reversing, device-scope atomics, memset-zeroed each replay).
// Phases: 1) sa map  2) per-plane sim  3) 64-block sort+nmax  4) gather.
// Block n owns planes 16n..16n+15 (same stream,b) in phases 2&4 -> sa staged
// in LDS once, reused. Inputs are L3-resident after phase 1.

#define CDIM   256
#define HWDIM  3136
#define CHW    (CDIM * HWDIM)        /* 802816 */
#define PAIRS  1568                  /* HWDIM/2 */
#define QUADS  784                   /* HWDIM/4 */
#define NBLK   1024
#define NTHR   256

typedef unsigned short u16;
typedef unsigned int   u32;

__device__ __forceinline__ float bf2f(u32 u) { return __uint_as_float(u << 16); }
__device__ __forceinline__ u16  f2bf(float f) {
    u32 x = __float_as_uint(f);
    return (u16)((x + 0x7FFFu + ((x >> 16) & 1u)) >> 16);   // RNE
}
__device__ __forceinline__ u32 pack2(u32 u, float s0, float s1) {
    float a0 = __uint_as_float(u << 16);
    float a1 = __uint_as_float(u & 0xFFFF0000u);
    u32 lo = f2bf(a0 * s0), hi = f2bf(a1 * s1);
    return lo | (hi << 16);
}
__device__ __forceinline__ u32 maxpack2(u32 u, u32 w, float s0, float s1) {
    float a0 = __uint_as_float(u << 16), a1 = __uint_as_float(u & 0xFFFF0000u);
    float b0 = __uint_as_float(w << 16), b1 = __uint_as_float(w & 0xFFFF0000u);
    u32 lo = f2bf(fmaxf(a0, b0) * s0), hi = f2bf(fmaxf(a1, b1) * s1);
    return lo | (hi << 16);
}

// Sense-reversing grid barrier. All NBLK blocks co-resident (exact-capacity
// grid with forced occupancy). cnt/gen zeroed by host-side memset per launch.
__device__ __forceinline__ void gsync(int* cnt, int* gen) {
    __threadfence();                 // flush this block's plain stores
    __syncthreads();
    if (threadIdx.x == 0) {
        int g = __hip_atomic_load(gen, __ATOMIC_RELAXED, __HIP_MEMORY_SCOPE_AGENT);
        int a = __hip_atomic_fetch_add(cnt, 1, __ATOMIC_ACQ_REL, __HIP_MEMORY_SCOPE_AGENT);
        if (a == NBLK - 1) {
            __hip_atomic_store(cnt, 0, __ATOMIC_RELAXED, __HIP_MEMORY_SCOPE_AGENT);
            __hip_atomic_store(gen, g + 1, __ATOMIC_RELEASE, __HIP_MEMORY_SCOPE_AGENT);
        } else {
            while (__hip_atomic_load(gen, __ATOMIC_ACQUIRE, __HIP_MEMORY_SCOPE_AGENT) == g) {
                __builtin_amdgcn_s_sleep(8);
            }
        }
    }
    __syncthreads();
}

__global__ __launch_bounds__(NTHR, 4) void k_fused(const void* __restrict__ rgb_,
                                                   const void* __restrict__ ir_,
                                                   int* __restrict__ wsi,
                                                   float* __restrict__ sa32,
                                                   double* __restrict__ sims,
                                                   int* __restrict__ ord,
                                                   void* __restrict__ out_) {
    int* bar_cnt = wsi + 0;
    int* bar_gen = wsi + 1;
    int* nmx     = wsi + 2;          // [2]

    __shared__ float  s_sa[HWDIM];   // 12544 B
    __shared__ double s_srt[256];    //  2048 B
    __shared__ int    s_ci;

    int tid = threadIdx.x, bid = blockIdx.x;
    int lane = tid & 63, wid = tid >> 6;

    // ---- dtype detect (per wave, reads first 256B of rgb; L2 broadcast).
    //      fp32 misread as bf16: ~46% weird halves; bf16 N(0,1): none. ----
    int wd = 0;
    {
        u32 u = ((const u32*)rgb_)[lane];
        u32 h0 = u & 0xFFFFu, h1 = u >> 16;
        int e0 = (h0 >> 7) & 0xFF, e1 = (h1 >> 7) & 0xFF;
        if (e0 == 0xFF || fabsf(bf2f(h0)) > 1e3f) wd++;
        if (e1 == 0xFF || fabsf(bf2f(h1)) > 1e3f) wd++;
    }
    #pragma unroll
    for (int off = 32; off >= 1; off >>= 1) wd += __shfl_xor(wd, off, 64);
    const int md = (wd > 8) ? 1 : 0;          // 0=bf16 1=fp32

    // ================= Phase 1: sa map =================
    // 3136 wave-tasks (32 b x 98 qgroups of 8 quads) over 4096 waves.
    // Wave: lane = qoff(0..7) + 8*sg(0..7); lane covers 32 channels.
    {
        int gw = bid * 4 + wid;
        if (gw < 3136) {
            int b  = gw / 98, qg = gw - b * 98;
            int qoff = lane & 7, sg = lane >> 3;
            int ql = qg * 8 + qoff;

            double s0 = 0.0, s1 = 0.0, s2 = 0.0, s3 = 0.0;
            float m0r = -INFINITY, m1r = -INFINITY, m2r = -INFINITY, m3r = -INFINITY;
            float m0i = -INFINITY, m1i = -INFINITY, m2i = -INFINITY, m3i = -INFINITY;

            if (md == 1) {
                const float4* R = (const float4*)rgb_ + (size_t)b * (CHW / 4)
                                  + (size_t)sg * QUADS + ql;
                const float4* I = (const float4*)ir_  + (size_t)b * (CHW / 4)
                                  + (size_t)sg * QUADS + ql;
                #pragma unroll 4
                for (int k = 0; k < 32; ++k) {
                    size_t o = (size_t)(8 * k) * QUADS;
                    float4 r = R[o];
                    float4 i = I[o];
                    s0 += (double)r.x + (double)i.x;
                    s1 += (double)r.y + (double)i.y;
                    s2 += (double)r.z + (double)i.z;
                    s3 += (double)r.w + (double)i.w;
                    m0r = fmaxf(m0r, r.x); m1r = fmaxf(m1r, r.y);
                    m2r = fmaxf(m2r, r.z); m3r = fmaxf(m3r, r.w);
                    m0i = fmaxf(m0i, i.x); m1i = fmaxf(m1i, i.y);
                    m2i = fmaxf(m2i, i.z); m3i = fmaxf(m3i, i.w);
                }
            } else {
                const uint2* R = (const uint2*)rgb_ + (size_t)b * (CHW / 4)
                                 + (size_t)sg * QUADS + ql;
                const uint2* I = (const uint2*)ir_  + (size_t)b * (CHW / 4)
                                 + (size_t)sg * QUADS + ql;
                #pragma unroll 4
                for (int k = 0; k < 32; ++k) {
                    size_t o = (size_t)(8 * k) * QUADS;
                    uint2 ur = R[o];
                    uint2 ui = I[o];
                    float r0 = bf2f(ur.x & 0xFFFFu), r1 = bf2f(ur.x >> 16);
                    float r2 = bf2f(ur.y & 0xFFFFu), r3 = bf2f(ur.y >> 16);
                    float i0 = bf2f(ui.x & 0xFFFFu), i1 = bf2f(ui.x >> 16);
                    float i2 = bf2f(ui.y & 0xFFFFu), i3 = bf2f(ui.y >> 16);
                    s0 += (double)r0 + (double)i0;
                    s1 += (double)r1 + (double)i1;
                    s2 += (double)r2 + (double)i2;
                    s3 += (double)r3 + (double)i3;
                    m0r = fmaxf(m0r, r0); m1r = fmaxf(m1r, r1);
                    m2r = fmaxf(m2r, r2); m3r = fmaxf(m3r, r3);
                    m0i = fmaxf(m0i, i0); m1i = fmaxf(m1i, i1);
                    m2i = fmaxf(m2i, i2); m3i = fmaxf(m3i, i3);
                }
            }

            // reduce over the 8 channel subgroups (xor lane bits 3,4,5)
            #pragma unroll
            for (int off = 8; off <= 32; off <<= 1) {
                s0 += __shfl_xor(s0, off, 64);
                s1 += __shfl_xor(s1, off, 64);
                s2 += __shfl_xor(s2, off, 64);
                s3 += __shfl_xor(s3, off, 64);
                m0r = fmaxf(m0r, __shfl_xor(m0r, off, 64));
                m1r = fmaxf(m1r, __shfl_xor(m1r, off, 64));
                m2r = fmaxf(m2r, __shfl_xor(m2r, off, 64));
                m3r = fmaxf(m3r, __shfl_xor(m3r, off, 64));
                m0i = fmaxf(m0i, __shfl_xor(m0i, off, 64));
                m1i = fmaxf(m1i, __shfl_xor(m1i, off, 64));
                m2i = fmaxf(m2i, __shfl_xor(m2i, off, 64));
                m3i = fmaxf(m3i, __shfl_xor(m3i, off, 64));
            }

            if (sg == 0) {
                double sa0 = fmax(s0 * (1.0 / 256.0), (double)m0r + (double)m0i);
                double sa1 = fmax(s1 * (1.0 / 256.0), (double)m1r + (double)m1i);
                double sa2 = fmax(s2 * (1.0 / 256.0), (double)m2r + (double)m2i);
                double sa3 = fmax(s3 * (1.0 / 256.0), (double)m3r + (double)m3i);
                float4 ov;
                ov.x = (float)(1.0 / (1.0 + exp(-sa0)));
                ov.y = (float)(1.0 / (1.0 + exp(-sa1)));
                ov.z = (float)(1.0 / (1.0 + exp(-sa2)));
                ov.w = (float)(1.0 / (1.0 + exp(-sa3)));
                *(float4*)&sa32[(size_t)b * HWDIM + 4 * (size_t)ql] = ov;
            }
        }
    }

    gsync(bar_cnt, bar_gen);

    // ================= Phase 2: similarities =================
    // block n -> planes 16n..16n+15 (same stream, same b). sa staged in LDS.
    int p0     = bid << 4;
    int stream = bid >> 9;
    int b2     = (bid >> 4) & 31;
    {
        const float4* src = (const float4*)(sa32 + (size_t)b2 * HWDIM);
        float4* dst = (float4*)s_sa;
        for (int i = tid; i < QUADS; i += NTHR) dst[i] = src[i];
    }
    __syncthreads();
    {
        const float4* sv = (const float4*)s_sa;
        for (int k = 0; k < 4; ++k) {
            int p = p0 + wid * 4 + k;
            int plane = p & 8191;            // b*256 + c
            double ss = 0.0, dot = 0.0;
            if (md == 1) {
                const float4* x = (const float4*)(stream ? ir_ : rgb_)
                                  + (size_t)plane * QUADS;
                #pragma unroll 2
                for (int j = lane; j < QUADS; j += 64) {
                    float4 v = x[j];
                    float4 s = sv[j];
                    ss  = fma((double)v.x, (double)v.x,
                          fma((double)v.y, (double)v.y,
                          fma((double)v.z, (double)v.z,
                          fma((double)v.w, (double)v.w, ss))));
                    dot = fma((double)s.x, (double)v.x,
                          fma((double)s.y, (double)v.y,
                          fma((double)s.z, (double)v.z,
                          fma((double)s.w, (double)v.w, dot))));
                }
            } else {
                const u32* x = (const u32*)(stream ? ir_ : rgb_)
                               + (size_t)plane * PAIRS;
                #pragma unroll 2
                for (int j = lane; j < QUADS; j += 64) {
                    u32 w0 = x[2 * j], w1 = x[2 * j + 1];
                    double v0 = (double)bf2f(w0 & 0xFFFFu), v1 = (double)bf2f(w0 >> 16);
                    double v2 = (double)bf2f(w1 & 0xFFFFu), v3 = (double)bf2f(w1 >> 16);
                    float4 s = sv[j];
                    ss  = fma(v0, v0, fma(v1, v1, fma(v2, v2, fma(v3, v3, ss))));
                    dot = fma((double)s.x, v0, fma((double)s.y, v1,
                          fma((double)s.z, v2, fma((double)s.w, v3, dot))));
                }
            }
            #pragma unroll
            for (int off = 32; off >= 1; off >>= 1) {
                ss  += __shfl_xor(ss,  off, 64);
                dot += __shfl_xor(dot, off, 64);
            }
            if (lane == 0) {
                double nrm = sqrt(ss);
                if (nrm < 1e-12) nrm = 1e-12;
                sims[p] = dot / nrm;
            }
        }
    }

    gsync(bar_cnt, bar_gen);

    // ================= Phase 3: sort (blocks 0..63) =================
    if (bid < 64) {
        int sb = bid;
        int c  = tid;
        double v = sims[sb * 256 + c];
        if (isnan(v)) v = -INFINITY;     // keep ranks a permutation
        s_srt[c] = v;
        if (c == 0) s_ci = 0;
        __syncthreads();
        int rank = 0;
        #pragma unroll 8
        for (int j = 0; j < 256; ++j) {
            double u = s_srt[j];
            rank += (u < v) || (u == v && j < c);
        }
        ord[sb * 256 + rank] = c;
        unsigned long long mB = __ballot(v > 0.0);
        if ((c & 63) == 0) atomicAdd(&s_ci, (int)__popcll(mB));
        __syncthreads();
        if (c == 0) atomicMax(&nmx[sb >> 5], s_ci);  // nmx zeroed by memset
    }

    gsync(bar_cnt, bar_gen);

    // ================= Phase 4: gather (16 output planes / block) ========
    {
        int n_self  = nmx[stream];
        int n_other = nmx[1 - stream];
        bool insert = n_other > n_self;
        const float4* sg4 = (const float4*)s_sa;    // still staged, same b2

        for (int k = 0; k < 16; ++k) {
            int po = p0 + k;                        // global output plane
            int co = po & 255;
            bool special = insert && (co == n_self);

            if (!special) {
                int ci = co;
                if (insert && co > n_self) ci = co - 1;
                int src = ord[(po & ~255) + ci] & 255;   // clamp: never OOB
                size_t pb = (size_t)(b2 * 256 + src) * HWDIM;
                if (md == 0) {
                    const u16* x = stream ? (const u16*)ir_ : (const u16*)rgb_;
                    const uint4* xin = (const uint4*)(x + pb);
                    uint4* o = (uint4*)((u16*)out_ + (size_t)po * HWDIM);
                    for (int i = tid; i < 392; i += NTHR) {
                        uint4 u = xin[i];
                        float4 sA = sg4[2 * i], sB = sg4[2 * i + 1];
                        uint4 r;
                        r.x = pack2(u.x, sA.x, sA.y);
                        r.y = pack2(u.y, sA.z, sA.w);
                        r.z = pack2(u.z, sB.x, sB.y);
                        r.w = pack2(u.w, sB.z, sB.w);
                        o[i] = r;
                    }
                } else {
                    const float* x = stream ? (const float*)ir_ : (const float*)rgb_;
                    const float4* xin = (const float4*)(x + pb);
                    float4* o = (float4*)((float*)out_ + (size_t)po * HWDIM);
                    for (int i = tid; i < 784; i += NTHR) {
                        float4 v = xin[i], s = sg4[i];
                        o[i] = make_float4(v.x * s.x, v.y * s.y, v.z * s.z, v.w * s.w);
                    }
                }
            } else {
                int src_r = ord[b2 * 256] & 255;
                int src_i = ord[8192 + b2 * 256] & 255;
                size_t pr = (size_t)(b2 * 256 + src_r) * HWDIM;
                size_t pi = (size_t)(b2 * 256 + src_i) * HWDIM;
                if (md == 0) {
                    const uint4* xr = (const uint4*)((const u16*)rgb_ + pr);
                    const uint4* xi = (const uint4*)((const u16*)ir_  + pi);
                    uint4* o = (uint4*)((u16*)out_ + (size_t)po * HWDIM);
                    for (int i = tid; i < 392; i += NTHR) {
                        uint4 u = xr[i], w = xi[i];
                        float4 sA = sg4[2 * i], sB = sg4[2 * i + 1];
                        uint4 r;
                        r.x = maxpack2(u.x, w.x, sA.x, sA.y);
                        r.y = maxpack2(u.y, w.y, sA.z, sA.w);
                        r.z = maxpack2(u.z, w.z, sB.x, sB.y);
                        r.w = maxpack2(u.w, w.w, sB.z, sB.w);
                        o[i] = r;
                    }
                } else {
                    const float4* xr = (const float4*)((const float*)rgb_ + pr);
                    const float4* xi = (const float4*)((const float*)ir_  + pi);
                    float4* o = (float4*)((float*)out_ + (size_t)po * HWDIM);
                    for (int i = tid; i < 784; i += NTHR) {
                        float4 u = xr[i], w = xi[i], s = sg4[i];
                        o[i] = make_float4(fmaxf(u.x, w.x) * s.x,
                                           fmaxf(u.y, w.y) * s.y,
                                           fmaxf(u.z, w.z) * s.z,
                                           fmaxf(u.w, w.w) * s.w);
                    }
                }
            }
        }
    }
}

extern "C" void kernel_launch(void* const* d_in, const int* in_sizes, int n_in,
                              void* d_out, int out_size, void* d_ws, size_t ws_size,
                              hipStream_t stream) {
    const void* rgb = d_in[0];
    const void* ir  = d_in[1];

    char* ws = (char*)d_ws;
    int*    wsi  = (int*)   ws;              // @ 0: bar_cnt, bar_gen, nmx[2]
    float*  sa32 = (float*) (ws + 1024);     // @ 1024    (401408 B)
    double* sims = (double*)(ws + 402432);   // @ 402432  (131072 B)
    int*    ord  = (int*)   (ws + 533504);   // @ 533504  (65536 B) total <600KB

    hipMemsetAsync(wsi, 0, 64, stream);      // barrier state + nmx, per replay
    hipLaunchKernelGGL(k_fused, dim3(NBLK), dim3(NTHR), 0, stream,
                       rgb, ir, wsi, sa32, sims, ord, d_out);
}